// Round 1
// baseline (130.723 us; speedup 1.0000x reference)
//
#include <hip/hip_runtime.h>

// Problem constants (match reference):
// N=100000, K=20, D=96, H=1024, C=7, RIDGE=100
#define D_DIM 96
#define K_NN  20
#define H_DIM 1024
#define C_CLS 7

// ---------------------------------------------------------------------------
// ws layout (bytes):
//   0       proto_n   672 f32   (2688 B)
//   4096    flags     [0]=masked_count(int) [1]=idx_is64(int)
//   4160    wo_flag   1 f32
//   8192    preds     N int32              (400000 B)
//   408192  list      N int32              (400000 B)
//   808192  Qn        1024*7 f32           (28672 B)
//   836864  wo        1024*7 f32           (28672 B)
//   865536  Gn        1024*1024 f32        (4194304 B)  -> total 5059840 B
// ---------------------------------------------------------------------------

__global__ void k_init(const float* __restrict__ proto,
                       const long long* __restrict__ idx_ll,
                       float* __restrict__ proto_n, int* __restrict__ flags) {
  __shared__ float inv[C_CLS];
  __shared__ int any_big;
  int t = threadIdx.x;
  if (t == 0) any_big = 0;
  if (t < C_CLS) {
    float ss = 0.f;
    for (int d = 0; d < D_DIM; d++) { float v = proto[t * D_DIM + d]; ss += v * v; }
    float nrm = fmaxf(sqrtf(ss), 1e-12f);
    inv[t] = 1.0f / nrm;
  }
  // dtype detection: sample first 1024 slots interpreted as int64.
  // int32 data read as int64 pairs two indices -> value >= 2^32 unless the
  // high word happens to be 0 (prob 1e-5 per slot).
  for (int j = t; j < 1024; j += blockDim.x) {
    long long v = idx_ll[j];
    if (v < 0 || v >= 100000) any_big = 1;  // benign race, all write 1
  }
  __syncthreads();
  for (int j = t; j < C_CLS * D_DIM; j += blockDim.x)
    proto_n[j] = proto[j] * inv[j / D_DIM];
  if (t == 0) {
    flags[0] = 0;                 // masked count
    flags[1] = any_big ? 0 : 1;   // is64
  }
}

__global__ void k_preds(const float* __restrict__ feat,
                        const float* __restrict__ proto_n,
                        int* __restrict__ preds, int N) {
  __shared__ float pn[C_CLS * D_DIM];
  for (int j = threadIdx.x; j < C_CLS * D_DIM; j += blockDim.x) pn[j] = proto_n[j];
  __syncthreads();
  int i = blockIdx.x * blockDim.x + threadIdx.x;
  if (i >= N) return;
  const float4* fp = (const float4*)(feat + (size_t)i * D_DIM);
  float s[C_CLS];
#pragma unroll
  for (int c = 0; c < C_CLS; c++) s[c] = 0.f;
#pragma unroll
  for (int q = 0; q < D_DIM / 4; q++) {
    float4 v = fp[q];
    int d = q * 4;
#pragma unroll
    for (int c = 0; c < C_CLS; c++) {
      s[c] += v.x * pn[c * D_DIM + d]     + v.y * pn[c * D_DIM + d + 1]
            + v.z * pn[c * D_DIM + d + 2] + v.w * pn[c * D_DIM + d + 3];
    }
  }
  float best = s[0]; int bi = 0;
#pragma unroll
  for (int c = 1; c < C_CLS; c++) { if (s[c] > best) { best = s[c]; bi = c; } }  // first-max, matches jnp.argmax
  preds[i] = bi;
}

__global__ void k_mask(const int* __restrict__ preds, const void* __restrict__ nearv,
                       const float* __restrict__ coords, const float* __restrict__ normz,
                       int* __restrict__ flags, int* __restrict__ list, int N) {
  int i = blockIdx.x * blockDim.x + threadIdx.x;
  if (i >= N) return;
  int p = preds[i];
  int cnt = 0;
  if (flags[1]) {
    const long long* nn = (const long long*)nearv + (long long)i * K_NN;
#pragma unroll
    for (int k = 0; k < K_NN; k++) cnt += (preds[(int)nn[k]] == p) ? 1 : 0;
  } else {
    const int* nn = (const int*)nearv + (size_t)i * K_NN;
#pragma unroll
    for (int k = 0; k < K_NN; k++) cnt += (preds[nn[k]] == p) ? 1 : 0;
  }
  bool cmask = (cnt >= 17);  // cnt/20 > 0.8  <=>  cnt >= 17 (exact in f32)
  bool plane = (p == 2) || (p == 3) || (p == 4);
  bool man   = (p == 5);
  bool other = (p == 0) || (p == 1) || (p == 6);
  float nz = normz[i];
  bool ground = plane && (nz > 0.9f) && (coords[(size_t)i * 3 + 2] < -10.0f);
  bool g = ground || other || man;
  bool m = (man && (nz < 0.1f)) || other || plane;
  if (cmask && g && m) {
    int pos = atomicAdd(&flags[0], 1);
    list[pos] = i;
  }
}

// Qn[h][c] = Q[h][c] + sum over masked rows of relu(feat_i . W[:,h]) * [pred_i==c]
__global__ void k_qn(const float* __restrict__ feat, const float* __restrict__ w,
                     const float* __restrict__ Q, const int* __restrict__ preds,
                     const int* __restrict__ flags, const int* __restrict__ list,
                     float* __restrict__ Qn) {
  int h = blockIdx.x * blockDim.x + threadIdx.x;  // 0..1023
  float q[C_CLS];
#pragma unroll
  for (int c = 0; c < C_CLS; c++) q[c] = Q[h * C_CLS + c];
  int M = flags[0];
  for (int m = 0; m < M; m++) {
    int i = list[m];
    float s = 0.f;
    for (int d = 0; d < D_DIM; d++) s += feat[(size_t)i * D_DIM + d] * w[(size_t)d * H_DIM + h];
    s = fmaxf(s, 0.f);
    q[preds[i]] += s;
  }
#pragma unroll
  for (int c = 0; c < C_CLS; c++) Qn[h * C_CLS + c] = q[c];
}

// Gn = G + F_m^T F_m over masked rows. 16x16 grid of 64x64 tiles, 256 thr/blk.
__global__ void k_gram(const float* __restrict__ feat, const float* __restrict__ w,
                       const float* __restrict__ G, const int* __restrict__ flags,
                       const int* __restrict__ list, float* __restrict__ Gn) {
  int bx = blockIdx.x & 15, by = blockIdx.x >> 4;
  int tr0 = by * 64, tc0 = bx * 64;
  __shared__ float fr[64], fc[64], fsh[D_DIM];
  float acc[4][4];
#pragma unroll
  for (int u = 0; u < 4; u++)
#pragma unroll
    for (int v = 0; v < 4; v++) acc[u][v] = 0.f;
  int M = flags[0];
  int t = threadIdx.x;
  int tu = t >> 4, tv = t & 15;
  for (int m = 0; m < M; m++) {
    int i = list[m];
    if (t < D_DIM) fsh[t] = feat[(size_t)i * D_DIM + t];
    __syncthreads();
    if (t < 64) {
      float s = 0.f;
      for (int d = 0; d < D_DIM; d++) s += fsh[d] * w[(size_t)d * H_DIM + tr0 + t];
      fr[t] = fmaxf(s, 0.f);
    } else if (t < 128) {
      int c = t - 64;
      float s = 0.f;
      for (int d = 0; d < D_DIM; d++) s += fsh[d] * w[(size_t)d * H_DIM + tc0 + c];
      fc[c] = fmaxf(s, 0.f);
    }
    __syncthreads();
#pragma unroll
    for (int u = 0; u < 4; u++)
#pragma unroll
      for (int v = 0; v < 4; v++) acc[u][v] += fr[tu * 4 + u] * fc[tv * 4 + v];
    __syncthreads();
  }
#pragma unroll
  for (int u = 0; u < 4; u++)
#pragma unroll
    for (int v = 0; v < 4; v++) {
      int r = tr0 + tu * 4 + u, c = tc0 + tv * 4 + v;
      Gn[(size_t)r * H_DIM + c] = G[(size_t)r * H_DIM + c] + acc[u][v];
    }
}

__device__ inline void block_reduce7(const float* val, volatile float* out,
                                     float* red) {
  int lane = threadIdx.x & 63, wave = threadIdx.x >> 6;
#pragma unroll
  for (int c = 0; c < C_CLS; c++) {
    float v = val[c];
#pragma unroll
    for (int o = 32; o > 0; o >>= 1) v += __shfl_down(v, o, 64);
    if (lane == 0) red[wave * C_CLS + c] = v;
  }
  __syncthreads();
  if (threadIdx.x == 0) {
#pragma unroll
    for (int c = 0; c < C_CLS; c++) {
      float s = 0.f;
      for (int wv = 0; wv < 16; wv++) s += red[wv * C_CLS + c];
      out[c] = s;
    }
  }
  __syncthreads();
}

// Block-CG on A = Gn + 100 I with 7 RHS. A is 100I + rank-M PSD, so CG
// converges in <= M+1 iterations exactly; with b=0 it exits at iteration 0.
__global__ void __launch_bounds__(1024) k_solve(const float* __restrict__ Gn,
                                                const float* __restrict__ Qn,
                                                float* __restrict__ wo,
                                                float* __restrict__ wo_flag) {
  const int h = threadIdx.x;
  __shared__ float psh[H_DIM * C_CLS];   // 28 KB
  __shared__ float red[16 * C_CLS];
  __shared__ float rs[C_CLS], bn2[C_CLS], pap[C_CLS], rsn[C_CLS];

  float x[C_CLS], r[C_CLS], p[C_CLS], t7[C_CLS];
#pragma unroll
  for (int c = 0; c < C_CLS; c++) {
    float b = Qn[h * C_CLS + c];
    x[c] = 0.f; r[c] = b; p[c] = b;
    t7[c] = b * b;
  }
  block_reduce7(t7, rs, red);
  if (h == 0) {
#pragma unroll
    for (int c = 0; c < C_CLS; c++) bn2[c] = rs[c];
  }
  __syncthreads();

  for (int it = 0; it < H_DIM; it++) {
    bool done = true;
#pragma unroll
    for (int c = 0; c < C_CLS; c++)
      done = done && (rs[c] <= bn2[c] * 1e-16f + 1e-30f);
    if (done) break;  // uniform: rs/bn2 live in LDS

#pragma unroll
    for (int c = 0; c < C_CLS; c++) psh[h * C_CLS + c] = p[c];
    __syncthreads();

    float ap[C_CLS];
#pragma unroll
    for (int c = 0; c < C_CLS; c++) ap[c] = 100.0f * p[c];
    const float* grow = Gn + (size_t)h * H_DIM;
    for (int k = 0; k < H_DIM; k++) {
      float g = grow[k];
#pragma unroll
      for (int c = 0; c < C_CLS; c++) ap[c] += g * psh[k * C_CLS + c];
    }
#pragma unroll
    for (int c = 0; c < C_CLS; c++) t7[c] = p[c] * ap[c];
    block_reduce7(t7, pap, red);

    float a[C_CLS], rsold[C_CLS];
#pragma unroll
    for (int c = 0; c < C_CLS; c++) {
      rsold[c] = rs[c];
      bool act = rs[c] > bn2[c] * 1e-16f + 1e-30f;
      a[c] = act ? rsold[c] / fmaxf(pap[c], 1e-37f) : 0.f;
    }
#pragma unroll
    for (int c = 0; c < C_CLS; c++) {
      x[c] += a[c] * p[c];
      r[c] -= a[c] * ap[c];
      t7[c] = r[c] * r[c];
    }
    block_reduce7(t7, rsn, red);
#pragma unroll
    for (int c = 0; c < C_CLS; c++) {
      float bb = rsn[c] / fmaxf(rsold[c], 1e-37f);
      p[c] = r[c] + bb * p[c];
    }
    if (h == 0) {
#pragma unroll
      for (int c = 0; c < C_CLS; c++) rs[c] = rsn[c];
    }
    __syncthreads();
  }

#pragma unroll
  for (int c = 0; c < C_CLS; c++) wo[h * C_CLS + c] = x[c];
  float s = 0.f;
#pragma unroll
  for (int c = 0; c < C_CLS; c++) s += fabsf(x[c]);
  t7[0] = s;
#pragma unroll
  for (int c = 1; c < C_CLS; c++) t7[c] = 0.f;
  block_reduce7(t7, rsn, red);
  if (h == 0) *wo_flag = rsn[0];
}

// out[i][c] = sum_h relu(feat_i . W[:,h]) * wo[h][c]. If wo == 0 (the
// data-driven common case here), this is exactly a zero fill.
__global__ void k_out(const float* __restrict__ feat, const float* __restrict__ w,
                      const float* __restrict__ wo, const float* __restrict__ wo_flag,
                      float* __restrict__ out, int N) {
  if (*wo_flag == 0.0f) {
    long long tid = (long long)blockIdx.x * blockDim.x + threadIdx.x;
    long long total = (long long)N * C_CLS;
    if (tid < total) out[tid] = 0.0f;
    return;
  }
  int i = blockIdx.x * blockDim.x + threadIdx.x;
  if (i >= N) return;
  float f[D_DIM];
  const float4* fp = (const float4*)(feat + (size_t)i * D_DIM);
#pragma unroll
  for (int q = 0; q < D_DIM / 4; q++) {
    float4 v = fp[q];
    f[4 * q] = v.x; f[4 * q + 1] = v.y; f[4 * q + 2] = v.z; f[4 * q + 3] = v.w;
  }
  float acc[C_CLS];
#pragma unroll
  for (int c = 0; c < C_CLS; c++) acc[c] = 0.f;
  for (int hh = 0; hh < H_DIM; hh++) {
    float s = 0.f;
#pragma unroll 8
    for (int d = 0; d < D_DIM; d++) s += f[d] * w[(size_t)d * H_DIM + hh];
    s = fmaxf(s, 0.f);
    const float* wrow = wo + hh * C_CLS;
#pragma unroll
    for (int c = 0; c < C_CLS; c++) acc[c] += s * wrow[c];
  }
#pragma unroll
  for (int c = 0; c < C_CLS; c++) out[(size_t)i * C_CLS + c] = acc[c];
}

extern "C" void kernel_launch(void* const* d_in, const int* in_sizes, int n_in,
                              void* d_out, int out_size, void* d_ws, size_t ws_size,
                              hipStream_t stream) {
  const float* feat   = (const float*)d_in[0];
  const float* proto  = (const float*)d_in[1];
  const float* w      = (const float*)d_in[2];
  const float* Q      = (const float*)d_in[3];
  const float* G      = (const float*)d_in[4];
  const float* coords = (const float*)d_in[5];
  const float* normz  = (const float*)d_in[6];
  const void*  nearv  = d_in[7];
  float* out = (float*)d_out;

  const int N = in_sizes[0] / D_DIM;  // 100000

  char* WS = (char*)d_ws;
  float* proto_n = (float*)(WS + 0);
  int*   flags   = (int*)(WS + 4096);
  float* wo_flag = (float*)(WS + 4160);
  int*   preds   = (int*)(WS + 8192);
  int*   list    = (int*)(WS + 8192 + 400000);
  float* Qn      = (float*)(WS + 808192);
  float* wo      = (float*)(WS + 836864);
  float* Gn      = (float*)(WS + 865536);
  // total ws need: 5059840 bytes
  if (ws_size < 5059840) return;  // constant per session; visible failure if hit

  int nblk = (N + 255) / 256;
  hipLaunchKernelGGL(k_init, dim3(1), dim3(256), 0, stream,
                     proto, (const long long*)nearv, proto_n, flags);
  hipLaunchKernelGGL(k_preds, dim3(nblk), dim3(256), 0, stream,
                     feat, proto_n, preds, N);
  hipLaunchKernelGGL(k_mask, dim3(nblk), dim3(256), 0, stream,
                     preds, nearv, coords, normz, flags, list, N);
  hipLaunchKernelGGL(k_qn, dim3(H_DIM / 256), dim3(256), 0, stream,
                     feat, w, Q, preds, flags, list, Qn);
  hipLaunchKernelGGL(k_gram, dim3(256), dim3(256), 0, stream,
                     feat, w, G, flags, list, Gn);
  hipLaunchKernelGGL(k_solve, dim3(1), dim3(1024), 0, stream,
                     Gn, Qn, wo, wo_flag);
  int oblk = (N * C_CLS + 255) / 256;
  hipLaunchKernelGGL(k_out, dim3(oblk), dim3(256), 0, stream,
                     feat, w, wo, wo_flag, out, N);
}

// Round 2
// 130.596 us; speedup vs baseline: 1.0010x; 1.0010x over previous
//
#include <hip/hip_runtime.h>

// Problem constants (match reference):
// N=100000, K=20, D=96, H=1024, C=7, RIDGE=100
#define D_DIM 96
#define K_NN  20
#define H_DIM 1024
#define C_CLS 7

// ---------------------------------------------------------------------------
// ws layout (bytes):
//   4096    flags     [0]=masked_count(int) [1]=idx_is64(int)
//   4160    wo_flag   1 f32
//   8192    preds     N int32              (400000 B)
//   408192  list      N int32              (400000 B)
//   808192  Qn        1024*7 f32           (28672 B)
//   836864  wo        1024*7 f32           (28672 B)
//   865536  Gn        1024*1024 f32        (4194304 B)  -> total 5059840 B
// ---------------------------------------------------------------------------

// Fused: proto normalization (per-block, tiny L2-cached read), flags init +
// index-dtype detection (block 0 only), and prototype-logit argmax for all N.
__global__ void k_preds(const float* __restrict__ feat,
                        const float* __restrict__ proto,
                        const long long* __restrict__ idx_ll,
                        int* __restrict__ preds, int* __restrict__ flags, int N) {
  __shared__ float pn[C_CLS * D_DIM];
  __shared__ float inv[C_CLS];
  __shared__ int any_big;
  if (threadIdx.x == 0) any_big = 0;
  if (threadIdx.x < C_CLS) {
    float ss = 0.f;
    for (int d = 0; d < D_DIM; d++) {
      float v = proto[threadIdx.x * D_DIM + d];
      ss += v * v;
    }
    inv[threadIdx.x] = 1.0f / fmaxf(sqrtf(ss), 1e-12f);
  }
  __syncthreads();
  for (int j = threadIdx.x; j < C_CLS * D_DIM; j += blockDim.x)
    pn[j] = proto[j] * inv[j / D_DIM];
  if (blockIdx.x == 0) {
    // dtype detection: sample first 1024 slots interpreted as int64.
    // int32 data read as int64 pairs two indices -> value >= 2^32 (or <0)
    // unless the high word happens to be 0 (prob ~1e-5 per slot, 1024 samples).
    for (int j = threadIdx.x; j < 1024; j += blockDim.x) {
      long long v = idx_ll[j];
      if (v < 0 || v >= N) any_big = 1;  // benign race, all write 1
    }
  }
  __syncthreads();
  if (blockIdx.x == 0 && threadIdx.x == 0) {
    flags[0] = 0;                 // masked count
    flags[1] = any_big ? 0 : 1;   // is64
  }
  int i = blockIdx.x * blockDim.x + threadIdx.x;
  if (i >= N) return;
  const float4* fp = (const float4*)(feat + (size_t)i * D_DIM);
  float s[C_CLS];
#pragma unroll
  for (int c = 0; c < C_CLS; c++) s[c] = 0.f;
#pragma unroll
  for (int q = 0; q < D_DIM / 4; q++) {
    float4 v = fp[q];
    int d = q * 4;
#pragma unroll
    for (int c = 0; c < C_CLS; c++) {
      s[c] += v.x * pn[c * D_DIM + d]     + v.y * pn[c * D_DIM + d + 1]
            + v.z * pn[c * D_DIM + d + 2] + v.w * pn[c * D_DIM + d + 3];
    }
  }
  float best = s[0]; int bi = 0;
#pragma unroll
  for (int c = 1; c < C_CLS; c++) { if (s[c] > best) { best = s[c]; bi = c; } }  // first-max, matches jnp.argmax
  preds[i] = bi;
}

__global__ void k_mask(const int* __restrict__ preds, const void* __restrict__ nearv,
                       const float* __restrict__ coords, const float* __restrict__ normz,
                       int* __restrict__ flags, int* __restrict__ list, int N) {
  int i = blockIdx.x * blockDim.x + threadIdx.x;
  if (i >= N) return;
  int p = preds[i];
  int cnt = 0;
  if (flags[1]) {
    const long long* nn = (const long long*)nearv + (long long)i * K_NN;
#pragma unroll
    for (int k = 0; k < K_NN; k++) cnt += (preds[(int)nn[k]] == p) ? 1 : 0;
  } else {
    const int* nn = (const int*)nearv + (size_t)i * K_NN;
#pragma unroll
    for (int k = 0; k < K_NN; k++) cnt += (preds[nn[k]] == p) ? 1 : 0;
  }
  bool cmask = (cnt >= 17);  // cnt/20 > 0.8  <=>  cnt >= 17 (exact in f32)
  bool plane = (p == 2) || (p == 3) || (p == 4);
  bool man   = (p == 5);
  bool other = (p == 0) || (p == 1) || (p == 6);
  float nz = normz[i];
  bool ground = plane && (nz > 0.9f) && (coords[(size_t)i * 3 + 2] < -10.0f);
  bool g = ground || other || man;
  bool m = (man && (nz < 0.1f)) || other || plane;
  if (cmask && g && m) {
    int pos = atomicAdd(&flags[0], 1);
    list[pos] = i;
  }
}

// Fused launch: blocks [0,1024) do a coalesced float4 copy Gn = G
// (1M floats = 262144 float4s = 1024 blocks * 256 threads); blocks
// [1024, 1028) compute Qn[h][c] = Q[h][c] + sum_masked relu(f_i.W[:,h])*[pred_i==c].
__global__ void k_qn_copy(const float* __restrict__ feat, const float* __restrict__ w,
                          const float* __restrict__ Q, const int* __restrict__ preds,
                          const int* __restrict__ flags, const int* __restrict__ list,
                          float* __restrict__ Qn,
                          const float* __restrict__ G, float* __restrict__ Gn) {
  if (blockIdx.x < 1024) {
    size_t t = (size_t)blockIdx.x * 256 + threadIdx.x;
    ((float4*)Gn)[t] = ((const float4*)G)[t];
    return;
  }
  int h = (blockIdx.x - 1024) * 256 + threadIdx.x;  // 0..1023
  float q[C_CLS];
#pragma unroll
  for (int c = 0; c < C_CLS; c++) q[c] = Q[h * C_CLS + c];
  int M = flags[0];
  for (int m = 0; m < M; m++) {
    int i = list[m];
    float s = 0.f;
    for (int d = 0; d < D_DIM; d++) s += feat[(size_t)i * D_DIM + d] * w[(size_t)d * H_DIM + h];
    s = fmaxf(s, 0.f);
    q[preds[i]] += s;
  }
#pragma unroll
  for (int c = 0; c < C_CLS; c++) Qn[h * C_CLS + c] = q[c];
}

// Gn += F_m^T F_m over masked rows (rank-M update). Runs AFTER the copy.
// Early-exits when M == 0 (data-dependent, identical code every call).
__global__ void k_gram_acc(const float* __restrict__ feat, const float* __restrict__ w,
                           const int* __restrict__ flags, const int* __restrict__ list,
                           float* __restrict__ Gn) {
  int M = flags[0];
  if (M == 0) return;
  int bx = blockIdx.x & 15, by = blockIdx.x >> 4;
  int tr0 = by * 64, tc0 = bx * 64;
  __shared__ float fr[64], fc[64], fsh[D_DIM];
  float acc[4][4];
#pragma unroll
  for (int u = 0; u < 4; u++)
#pragma unroll
    for (int v = 0; v < 4; v++) acc[u][v] = 0.f;
  int t = threadIdx.x;
  int tu = t >> 4, tv = t & 15;
  for (int m = 0; m < M; m++) {
    int i = list[m];
    if (t < D_DIM) fsh[t] = feat[(size_t)i * D_DIM + t];
    __syncthreads();
    if (t < 64) {
      float s = 0.f;
      for (int d = 0; d < D_DIM; d++) s += fsh[d] * w[(size_t)d * H_DIM + tr0 + t];
      fr[t] = fmaxf(s, 0.f);
    } else if (t < 128) {
      int c = t - 64;
      float s = 0.f;
      for (int d = 0; d < D_DIM; d++) s += fsh[d] * w[(size_t)d * H_DIM + tc0 + c];
      fc[c] = fmaxf(s, 0.f);
    }
    __syncthreads();
#pragma unroll
    for (int u = 0; u < 4; u++)
#pragma unroll
      for (int v = 0; v < 4; v++) acc[u][v] += fr[tu * 4 + u] * fc[tv * 4 + v];
    __syncthreads();
  }
#pragma unroll
  for (int u = 0; u < 4; u++)
#pragma unroll
    for (int v = 0; v < 4; v++) {
      int r = tr0 + tu * 4 + u, c = tc0 + tv * 4 + v;
      Gn[(size_t)r * H_DIM + c] += acc[u][v];
    }
}

__device__ inline void block_reduce7(const float* val, volatile float* out,
                                     float* red) {
  int lane = threadIdx.x & 63, wave = threadIdx.x >> 6;
#pragma unroll
  for (int c = 0; c < C_CLS; c++) {
    float v = val[c];
#pragma unroll
    for (int o = 32; o > 0; o >>= 1) v += __shfl_down(v, o, 64);
    if (lane == 0) red[wave * C_CLS + c] = v;
  }
  __syncthreads();
  if (threadIdx.x == 0) {
#pragma unroll
    for (int c = 0; c < C_CLS; c++) {
      float s = 0.f;
      for (int wv = 0; wv < 16; wv++) s += red[wv * C_CLS + c];
      out[c] = s;
    }
  }
  __syncthreads();
}

// Block-CG on A = Gn + 100 I with 7 RHS. A is 100I + rank-M PSD, so CG
// converges in <= M+1 iterations exactly; with b=0 it exits at iteration 0.
__global__ void __launch_bounds__(1024) k_solve(const float* __restrict__ Gn,
                                                const float* __restrict__ Qn,
                                                float* __restrict__ wo,
                                                float* __restrict__ wo_flag) {
  const int h = threadIdx.x;
  __shared__ float psh[H_DIM * C_CLS];   // 28 KB
  __shared__ float red[16 * C_CLS];
  __shared__ float rs[C_CLS], bn2[C_CLS], pap[C_CLS], rsn[C_CLS];

  float x[C_CLS], r[C_CLS], p[C_CLS], t7[C_CLS];
#pragma unroll
  for (int c = 0; c < C_CLS; c++) {
    float b = Qn[h * C_CLS + c];
    x[c] = 0.f; r[c] = b; p[c] = b;
    t7[c] = b * b;
  }
  block_reduce7(t7, rs, red);
  if (h == 0) {
#pragma unroll
    for (int c = 0; c < C_CLS; c++) bn2[c] = rs[c];
  }
  __syncthreads();

  for (int it = 0; it < H_DIM; it++) {
    bool done = true;
#pragma unroll
    for (int c = 0; c < C_CLS; c++)
      done = done && (rs[c] <= bn2[c] * 1e-16f + 1e-30f);
    if (done) break;  // uniform: rs/bn2 live in LDS

#pragma unroll
    for (int c = 0; c < C_CLS; c++) psh[h * C_CLS + c] = p[c];
    __syncthreads();

    float ap[C_CLS];
#pragma unroll
    for (int c = 0; c < C_CLS; c++) ap[c] = 100.0f * p[c];
    const float* grow = Gn + (size_t)h * H_DIM;
    for (int k = 0; k < H_DIM; k++) {
      float g = grow[k];
#pragma unroll
      for (int c = 0; c < C_CLS; c++) ap[c] += g * psh[k * C_CLS + c];
    }
#pragma unroll
    for (int c = 0; c < C_CLS; c++) t7[c] = p[c] * ap[c];
    block_reduce7(t7, pap, red);

    float a[C_CLS], rsold[C_CLS];
#pragma unroll
    for (int c = 0; c < C_CLS; c++) {
      rsold[c] = rs[c];
      bool act = rs[c] > bn2[c] * 1e-16f + 1e-30f;
      a[c] = act ? rsold[c] / fmaxf(pap[c], 1e-37f) : 0.f;
    }
#pragma unroll
    for (int c = 0; c < C_CLS; c++) {
      x[c] += a[c] * p[c];
      r[c] -= a[c] * ap[c];
      t7[c] = r[c] * r[c];
    }
    block_reduce7(t7, rsn, red);
#pragma unroll
    for (int c = 0; c < C_CLS; c++) {
      float bb = rsn[c] / fmaxf(rsold[c], 1e-37f);
      p[c] = r[c] + bb * p[c];
    }
    if (h == 0) {
#pragma unroll
      for (int c = 0; c < C_CLS; c++) rs[c] = rsn[c];
    }
    __syncthreads();
  }

#pragma unroll
  for (int c = 0; c < C_CLS; c++) wo[h * C_CLS + c] = x[c];
  float s = 0.f;
#pragma unroll
  for (int c = 0; c < C_CLS; c++) s += fabsf(x[c]);
  t7[0] = s;
#pragma unroll
  for (int c = 1; c < C_CLS; c++) t7[c] = 0.f;
  block_reduce7(t7, rsn, red);
  if (h == 0) *wo_flag = rsn[0];
}

// out[i][c] = sum_h relu(feat_i . W[:,h]) * wo[h][c]. If wo == 0 (the
// data-driven common case here), this is exactly a zero fill.
__global__ void k_out(const float* __restrict__ feat, const float* __restrict__ w,
                      const float* __restrict__ wo, const float* __restrict__ wo_flag,
                      float* __restrict__ out, int N) {
  if (*wo_flag == 0.0f) {
    long long tid = (long long)blockIdx.x * blockDim.x + threadIdx.x;
    long long total = (long long)N * C_CLS;
    if (tid < total) out[tid] = 0.0f;
    return;
  }
  int i = blockIdx.x * blockDim.x + threadIdx.x;
  if (i >= N) return;
  float f[D_DIM];
  const float4* fp = (const float4*)(feat + (size_t)i * D_DIM);
#pragma unroll
  for (int q = 0; q < D_DIM / 4; q++) {
    float4 v = fp[q];
    f[4 * q] = v.x; f[4 * q + 1] = v.y; f[4 * q + 2] = v.z; f[4 * q + 3] = v.w;
  }
  float acc[C_CLS];
#pragma unroll
  for (int c = 0; c < C_CLS; c++) acc[c] = 0.f;
  for (int hh = 0; hh < H_DIM; hh++) {
    float s = 0.f;
#pragma unroll 8
    for (int d = 0; d < D_DIM; d++) s += f[d] * w[(size_t)d * H_DIM + hh];
    s = fmaxf(s, 0.f);
    const float* wrow = wo + hh * C_CLS;
#pragma unroll
    for (int c = 0; c < C_CLS; c++) acc[c] += s * wrow[c];
  }
#pragma unroll
  for (int c = 0; c < C_CLS; c++) out[(size_t)i * C_CLS + c] = acc[c];
}

extern "C" void kernel_launch(void* const* d_in, const int* in_sizes, int n_in,
                              void* d_out, int out_size, void* d_ws, size_t ws_size,
                              hipStream_t stream) {
  const float* feat   = (const float*)d_in[0];
  const float* proto  = (const float*)d_in[1];
  const float* w      = (const float*)d_in[2];
  const float* Q      = (const float*)d_in[3];
  const float* G      = (const float*)d_in[4];
  const float* coords = (const float*)d_in[5];
  const float* normz  = (const float*)d_in[6];
  const void*  nearv  = d_in[7];
  float* out = (float*)d_out;

  const int N = in_sizes[0] / D_DIM;  // 100000

  char* WS = (char*)d_ws;
  int*   flags   = (int*)(WS + 4096);
  float* wo_flag = (float*)(WS + 4160);
  int*   preds   = (int*)(WS + 8192);
  int*   list    = (int*)(WS + 8192 + 400000);
  float* Qn      = (float*)(WS + 808192);
  float* wo      = (float*)(WS + 836864);
  float* Gn      = (float*)(WS + 865536);
  // total ws need: 5059840 bytes
  if (ws_size < 5059840) return;  // constant per session; visible failure if hit

  int nblk = (N + 255) / 256;
  hipLaunchKernelGGL(k_preds, dim3(nblk), dim3(256), 0, stream,
                     feat, proto, (const long long*)nearv, preds, flags, N);
  hipLaunchKernelGGL(k_mask, dim3(nblk), dim3(256), 0, stream,
                     preds, nearv, coords, normz, flags, list, N);
  hipLaunchKernelGGL(k_qn_copy, dim3(1024 + H_DIM / 256), dim3(256), 0, stream,
                     feat, w, Q, preds, flags, list, Qn, G, Gn);
  hipLaunchKernelGGL(k_gram_acc, dim3(256), dim3(256), 0, stream,
                     feat, w, flags, list, Gn);
  hipLaunchKernelGGL(k_solve, dim3(1), dim3(1024), 0, stream,
                     Gn, Qn, wo, wo_flag);
  int oblk = (N * C_CLS + 255) / 256;
  hipLaunchKernelGGL(k_out, dim3(oblk), dim3(256), 0, stream,
                     feat, w, wo, wo_flag, out, N);
}

// Round 3
// 126.578 us; speedup vs baseline: 1.0327x; 1.0317x over previous
//
#include <hip/hip_runtime.h>

// Problem constants (match reference):
// N=100000, K=20, D=96, H=1024, C=7, RIDGE=100
#define D_DIM 96
#define K_NN  20
#define H_DIM 1024
#define C_CLS 7

// ---------------------------------------------------------------------------
// ws layout (bytes):
//   4096    flags     [0]=masked_count(int) [1]=idx_is64(int)
//   4160    wo_flag   1 f32
//   8192    preds     N int32              (400000 B)
//   408192  list      N int32              (400000 B)
//   836864  wo        1024*7 f32           (28672 B)
//   865536  Gn        1024*1024 f32        (4194304 B)  -> total 5059840 B
// ---------------------------------------------------------------------------

// K1: proto staging+normalization (float4, LDS), flags init + index-dtype
// detection (block 0), prototype-logit argmax. 2 points per thread.
__global__ void k_preds(const float* __restrict__ feat,
                        const float* __restrict__ proto,
                        const long long* __restrict__ idx_ll,
                        int* __restrict__ preds, int* __restrict__ flags, int N) {
  __shared__ float4 pn4[C_CLS * (D_DIM / 4)];  // 168 float4
  __shared__ float inv[C_CLS];
  __shared__ int any_big;
  const int t = threadIdx.x;
  if (t == 0) any_big = 0;
  if (t < C_CLS * (D_DIM / 4)) pn4[t] = ((const float4*)proto)[t];
  if (blockIdx.x == 0) {
    // dtype detection: sample first 1024 slots interpreted as int64.
    // int32 data read as int64 pairs two indices -> value >= 2^32 (or <0)
    // unless the paired high word is 0 (prob 1e-5 per slot, 1024 samples).
    for (int j = t; j < 1024; j += blockDim.x) {
      long long v = idx_ll[j];
      if (v < 0 || v >= N) any_big = 1;  // benign race, all write 1
    }
  }
  __syncthreads();
  if (t < C_CLS) {
    const float* row = (const float*)&pn4[t * (D_DIM / 4)];
    float ss = 0.f;
    for (int d = 0; d < D_DIM; d++) ss += row[d] * row[d];
    inv[t] = 1.0f / fmaxf(sqrtf(ss), 1e-12f);
  }
  __syncthreads();
  if (t < C_CLS * (D_DIM / 4)) {
    float s = inv[t / (D_DIM / 4)];
    float4 v = pn4[t];
    v.x *= s; v.y *= s; v.z *= s; v.w *= s;
    pn4[t] = v;
  }
  if (blockIdx.x == 0 && t == 0) {
    flags[0] = 0;                 // masked count
    flags[1] = any_big ? 0 : 1;   // is64
  }
  __syncthreads();

  int i0 = blockIdx.x * 512 + t;
  int i1 = i0 + 256;
  int j0 = min(i0, N - 1), j1 = min(i1, N - 1);  // branchless tail (dup of last row)
  const float4* f0p = (const float4*)feat + (size_t)j0 * (D_DIM / 4);
  const float4* f1p = (const float4*)feat + (size_t)j1 * (D_DIM / 4);
  float s0[C_CLS], s1[C_CLS];
#pragma unroll
  for (int c = 0; c < C_CLS; c++) { s0[c] = 0.f; s1[c] = 0.f; }
#pragma unroll 4
  for (int q = 0; q < D_DIM / 4; q++) {
    float4 a = f0p[q];
    float4 b = f1p[q];
#pragma unroll
    for (int c = 0; c < C_CLS; c++) {
      float4 p = pn4[c * (D_DIM / 4) + q];  // wave-uniform LDS broadcast, b128
      s0[c] += a.x * p.x + a.y * p.y + a.z * p.z + a.w * p.w;
      s1[c] += b.x * p.x + b.y * p.y + b.z * p.z + b.w * p.w;
    }
  }
  float b0 = s0[0]; int a0 = 0;
  float b1 = s1[0]; int a1 = 0;
#pragma unroll
  for (int c = 1; c < C_CLS; c++) {  // strict >, first-max: matches jnp.argmax
    if (s0[c] > b0) { b0 = s0[c]; a0 = c; }
    if (s1[c] > b1) { b1 = s1[c]; a1 = c; }
  }
  if (i0 < N) preds[i0] = a0;
  if (i1 < N) preds[i1] = a1;
}

// K2: KNN-consistency + prior-filter mask + list compaction, PLUS a
// grid-stride float4 copy Gn = G (independent work, overlaps gather latency).
__global__ void k_mask_copy(const int* __restrict__ preds, const void* __restrict__ nearv,
                            const float* __restrict__ coords, const float* __restrict__ normz,
                            int* __restrict__ flags, int* __restrict__ list,
                            const float* __restrict__ G, float* __restrict__ Gn, int N) {
  // copy part: H*H floats = 262144 float4s over the whole grid
  {
    const int total4 = (H_DIM * H_DIM) / 4;
    int stride = gridDim.x * blockDim.x;
    for (int v = blockIdx.x * blockDim.x + threadIdx.x; v < total4; v += stride)
      ((float4*)Gn)[v] = ((const float4*)G)[v];
  }
  int i = blockIdx.x * blockDim.x + threadIdx.x;
  if (i >= N) return;
  int p = preds[i];
  int idx[K_NN];
  if (flags[1]) {
    const longlong2* nn = (const longlong2*)((const long long*)nearv + (long long)i * K_NN);
#pragma unroll
    for (int k = 0; k < K_NN / 2; k++) {
      longlong2 v = nn[k];
      idx[2 * k] = (int)v.x; idx[2 * k + 1] = (int)v.y;
    }
  } else {
    const int4* nn = (const int4*)((const int*)nearv + (size_t)i * K_NN);
#pragma unroll
    for (int k = 0; k < K_NN / 4; k++) {
      int4 v = nn[k];
      idx[4 * k] = v.x; idx[4 * k + 1] = v.y; idx[4 * k + 2] = v.z; idx[4 * k + 3] = v.w;
    }
  }
  int cnt = 0;
#pragma unroll
  for (int k = 0; k < K_NN; k++) cnt += (preds[idx[k]] == p) ? 1 : 0;
  bool cmask = (cnt >= 17);  // cnt/20 > 0.8  <=>  cnt >= 17 (exact in f32)
  bool plane = (p == 2) || (p == 3) || (p == 4);
  bool man   = (p == 5);
  bool other = (p == 0) || (p == 1) || (p == 6);
  float nz = normz[i];
  bool ground = plane && (nz > 0.9f) && (coords[(size_t)i * 3 + 2] < -10.0f);
  bool g = ground || other || man;
  bool m = (man && (nz < 0.1f)) || other || plane;
  if (cmask && g && m) {
    int pos = atomicAdd(&flags[0], 1);
    list[pos] = i;
  }
}

__device__ inline void block_reduce7(const float* val, volatile float* out,
                                     float* red) {
  int lane = threadIdx.x & 63, wave = threadIdx.x >> 6;
#pragma unroll
  for (int c = 0; c < C_CLS; c++) {
    float v = val[c];
#pragma unroll
    for (int o = 32; o > 0; o >>= 1) v += __shfl_down(v, o, 64);
    if (lane == 0) red[wave * C_CLS + c] = v;
  }
  __syncthreads();
  if (threadIdx.x == 0) {
#pragma unroll
    for (int c = 0; c < C_CLS; c++) {
      float s = 0.f;
      for (int wv = 0; wv < 16; wv++) s += red[wv * C_CLS + c];
      out[c] = s;
    }
  }
  __syncthreads();
}

// K3: single block, 1024 threads. Computes b = Qn row-block in registers
// (loop over masked list; M==0 -> skip), applies the rank-M Gram update to
// Gn if M>0 (slow-but-correct general path; empty in this data regime),
// then block-CG on A = Gn + 100 I with 7 RHS. A = 100I + rank-M PSD, so CG
// converges in <= M+1 iterations exactly; with b=0 it exits at iteration 0.
__global__ void __launch_bounds__(1024) k_ridge(const float* __restrict__ feat,
                                                const float* __restrict__ w,
                                                const float* __restrict__ Q,
                                                const int* __restrict__ preds,
                                                const int* __restrict__ flags,
                                                const int* __restrict__ list,
                                                float* __restrict__ Gn,
                                                float* __restrict__ wo,
                                                float* __restrict__ wo_flag) {
  const int h = threadIdx.x;
  __shared__ float psh[H_DIM * C_CLS];   // 28 KB (reused: f-staging then CG p)
  __shared__ float red[16 * C_CLS];
  __shared__ float rs[C_CLS], bn2[C_CLS], pap[C_CLS], rsn[C_CLS];

  const int M = flags[0];
  float b[C_CLS];
#pragma unroll
  for (int c = 0; c < C_CLS; c++) b[c] = Q[h * C_CLS + c];
  for (int m = 0; m < M; m++) {
    int i = list[m];
    float s = 0.f;
    for (int d = 0; d < D_DIM; d++)
      s += feat[(size_t)i * D_DIM + d] * w[(size_t)d * H_DIM + h];
    s = fmaxf(s, 0.f);
    b[preds[i]] += s;
    psh[h] = s;
    __syncthreads();
    float sh = psh[h];
    for (int k = 0; k < H_DIM; k++)
      Gn[(size_t)h * H_DIM + k] += sh * psh[k];
    __syncthreads();
  }

  float x[C_CLS], r[C_CLS], p[C_CLS], t7[C_CLS];
#pragma unroll
  for (int c = 0; c < C_CLS; c++) {
    x[c] = 0.f; r[c] = b[c]; p[c] = b[c];
    t7[c] = b[c] * b[c];
  }
  block_reduce7(t7, rs, red);
  if (h == 0) {
#pragma unroll
    for (int c = 0; c < C_CLS; c++) bn2[c] = rs[c];
  }
  __syncthreads();

  for (int it = 0; it < H_DIM; it++) {
    bool done = true;
#pragma unroll
    for (int c = 0; c < C_CLS; c++)
      done = done && (rs[c] <= bn2[c] * 1e-16f + 1e-30f);
    if (done) break;  // uniform: rs/bn2 live in LDS

#pragma unroll
    for (int c = 0; c < C_CLS; c++) psh[h * C_CLS + c] = p[c];
    __syncthreads();

    float ap[C_CLS];
#pragma unroll
    for (int c = 0; c < C_CLS; c++) ap[c] = 100.0f * p[c];
    const float* grow = Gn + (size_t)h * H_DIM;
    for (int k = 0; k < H_DIM; k++) {
      float g = grow[k];
#pragma unroll
      for (int c = 0; c < C_CLS; c++) ap[c] += g * psh[k * C_CLS + c];
    }
#pragma unroll
    for (int c = 0; c < C_CLS; c++) t7[c] = p[c] * ap[c];
    block_reduce7(t7, pap, red);

    float a[C_CLS], rsold[C_CLS];
#pragma unroll
    for (int c = 0; c < C_CLS; c++) {
      rsold[c] = rs[c];
      bool act = rs[c] > bn2[c] * 1e-16f + 1e-30f;
      a[c] = act ? rsold[c] / fmaxf(pap[c], 1e-37f) : 0.f;
    }
#pragma unroll
    for (int c = 0; c < C_CLS; c++) {
      x[c] += a[c] * p[c];
      r[c] -= a[c] * ap[c];
      t7[c] = r[c] * r[c];
    }
    block_reduce7(t7, rsn, red);
#pragma unroll
    for (int c = 0; c < C_CLS; c++) {
      float bb = rsn[c] / fmaxf(rsold[c], 1e-37f);
      p[c] = r[c] + bb * p[c];
    }
    if (h == 0) {
#pragma unroll
      for (int c = 0; c < C_CLS; c++) rs[c] = rsn[c];
    }
    __syncthreads();
  }

#pragma unroll
  for (int c = 0; c < C_CLS; c++) wo[h * C_CLS + c] = x[c];
  float s = 0.f;
#pragma unroll
  for (int c = 0; c < C_CLS; c++) s += fabsf(x[c]);
  t7[0] = s;
#pragma unroll
  for (int c = 1; c < C_CLS; c++) t7[c] = 0.f;
  block_reduce7(t7, rsn, red);
  if (h == 0) *wo_flag = rsn[0];
}

// K4: out[i][c] = sum_h relu(feat_i . W[:,h]) * wo[h][c]. If wo == 0 (the
// data-driven common case here), this is exactly a zero fill.
__global__ void k_out(const float* __restrict__ feat, const float* __restrict__ w,
                      const float* __restrict__ wo, const float* __restrict__ wo_flag,
                      float* __restrict__ out, int N) {
  if (*wo_flag == 0.0f) {
    long long tid = (long long)blockIdx.x * blockDim.x + threadIdx.x;
    long long total = (long long)N * C_CLS;
    if (tid < total) out[tid] = 0.0f;
    return;
  }
  int i = blockIdx.x * blockDim.x + threadIdx.x;
  if (i >= N) return;
  float f[D_DIM];
  const float4* fp = (const float4*)(feat + (size_t)i * D_DIM);
#pragma unroll
  for (int q = 0; q < D_DIM / 4; q++) {
    float4 v = fp[q];
    f[4 * q] = v.x; f[4 * q + 1] = v.y; f[4 * q + 2] = v.z; f[4 * q + 3] = v.w;
  }
  float acc[C_CLS];
#pragma unroll
  for (int c = 0; c < C_CLS; c++) acc[c] = 0.f;
  for (int hh = 0; hh < H_DIM; hh++) {
    float s = 0.f;
#pragma unroll 8
    for (int d = 0; d < D_DIM; d++) s += f[d] * w[(size_t)d * H_DIM + hh];
    s = fmaxf(s, 0.f);
    const float* wrow = wo + hh * C_CLS;
#pragma unroll
    for (int c = 0; c < C_CLS; c++) acc[c] += s * wrow[c];
  }
#pragma unroll
  for (int c = 0; c < C_CLS; c++) out[(size_t)i * C_CLS + c] = acc[c];
}

extern "C" void kernel_launch(void* const* d_in, const int* in_sizes, int n_in,
                              void* d_out, int out_size, void* d_ws, size_t ws_size,
                              hipStream_t stream) {
  const float* feat   = (const float*)d_in[0];
  const float* proto  = (const float*)d_in[1];
  const float* w      = (const float*)d_in[2];
  const float* Q      = (const float*)d_in[3];
  const float* G      = (const float*)d_in[4];
  const float* coords = (const float*)d_in[5];
  const float* normz  = (const float*)d_in[6];
  const void*  nearv  = d_in[7];
  float* out = (float*)d_out;

  const int N = in_sizes[0] / D_DIM;  // 100000

  char* WS = (char*)d_ws;
  int*   flags   = (int*)(WS + 4096);
  float* wo_flag = (float*)(WS + 4160);
  int*   preds   = (int*)(WS + 8192);
  int*   list    = (int*)(WS + 8192 + 400000);
  float* wo      = (float*)(WS + 836864);
  float* Gn      = (float*)(WS + 865536);
  // total ws need: 5059840 bytes
  if (ws_size < 5059840) return;  // constant per session; visible failure if hit

  int pblk = (N + 511) / 512;   // 2 points per thread
  hipLaunchKernelGGL(k_preds, dim3(pblk), dim3(256), 0, stream,
                     feat, proto, (const long long*)nearv, preds, flags, N);
  int nblk = (N + 255) / 256;
  hipLaunchKernelGGL(k_mask_copy, dim3(nblk), dim3(256), 0, stream,
                     preds, nearv, coords, normz, flags, list, G, Gn, N);
  hipLaunchKernelGGL(k_ridge, dim3(1), dim3(1024), 0, stream,
                     feat, w, Q, preds, flags, list, Gn, wo, wo_flag);
  int oblk = (N * C_CLS + 255) / 256;
  hipLaunchKernelGGL(k_out, dim3(oblk), dim3(256), 0, stream,
                     feat, w, wo, wo_flag, out, N);
}

// Round 4
// 120.162 us; speedup vs baseline: 1.0879x; 1.0534x over previous
//
#include <hip/hip_runtime.h>

// Problem constants (match reference):
// N=100000, K=20, D=96, H=1024, C=7, RIDGE=100
#define D_DIM 96
#define K_NN  20
#define H_DIM 1024
#define C_CLS 7

// ---------------------------------------------------------------------------
// ws layout (bytes):
//   4096    flags     [0]=masked_count(int) [1]=idx_is64(int)
//   4160    wo_flag   1 f32
//   8192    preds     N int32              (400000 B)
//   408192  list      N int32              (400000 B)
//   836864  wo        1024*7 f32           (28672 B)
//   865536  Gn        1024*1024 f32        (4194304 B; only touched if M>0)
//   total need: 5059840 B
// ---------------------------------------------------------------------------

// K1: proto staging+normalization (float4, LDS), flags init + index-dtype
// detection (block 0), prototype-logit argmax. 1 point per thread, 391 blocks
// (1.5 blocks/CU -> all CUs pulling HBM; 2 pts/thread left 60 CUs idle).
__global__ void k_preds(const float* __restrict__ feat,
                        const float* __restrict__ proto,
                        const long long* __restrict__ idx_ll,
                        int* __restrict__ preds, int* __restrict__ flags, int N) {
  __shared__ float4 pn4[C_CLS * (D_DIM / 4)];  // 168 float4
  __shared__ float inv[C_CLS];
  __shared__ int any_big;
  const int t = threadIdx.x;
  if (t == 0) any_big = 0;
  if (t < C_CLS * (D_DIM / 4)) pn4[t] = ((const float4*)proto)[t];
  if (blockIdx.x == 0) {
    // dtype detection: sample first 1024 slots interpreted as int64.
    // int32 data read as int64 pairs two indices -> value >= 2^32 (or <0)
    // unless the paired high word is 0 (prob ~1e-5 per slot, 1024 samples).
    for (int j = t; j < 1024; j += blockDim.x) {
      long long v = idx_ll[j];
      if (v < 0 || v >= N) any_big = 1;  // benign race, all write 1
    }
  }
  __syncthreads();
  if (t < C_CLS) {
    const float* row = (const float*)&pn4[t * (D_DIM / 4)];
    float ss = 0.f;
    for (int d = 0; d < D_DIM; d++) ss += row[d] * row[d];
    inv[t] = 1.0f / fmaxf(sqrtf(ss), 1e-12f);
  }
  __syncthreads();
  if (t < C_CLS * (D_DIM / 4)) {
    float s = inv[t / (D_DIM / 4)];
    float4 v = pn4[t];
    v.x *= s; v.y *= s; v.z *= s; v.w *= s;
    pn4[t] = v;
  }
  if (blockIdx.x == 0 && t == 0) {
    flags[0] = 0;                 // masked count
    flags[1] = any_big ? 0 : 1;   // is64
  }
  __syncthreads();

  int i = blockIdx.x * blockDim.x + t;
  int j = min(i, N - 1);  // branchless tail (dup of last row)
  const float4* fp = (const float4*)feat + (size_t)j * (D_DIM / 4);
  float s[C_CLS];
#pragma unroll
  for (int c = 0; c < C_CLS; c++) s[c] = 0.f;
#pragma unroll 4
  for (int q = 0; q < D_DIM / 4; q++) {
    float4 a = fp[q];
#pragma unroll
    for (int c = 0; c < C_CLS; c++) {
      float4 p = pn4[c * (D_DIM / 4) + q];  // wave-uniform LDS broadcast, b128
      s[c] += a.x * p.x + a.y * p.y + a.z * p.z + a.w * p.w;
    }
  }
  float best = s[0]; int bi = 0;
#pragma unroll
  for (int c = 1; c < C_CLS; c++)  // strict >, first-max: matches jnp.argmax
    if (s[c] > best) { best = s[c]; bi = c; }
  if (i < N) preds[i] = bi;
}

// K2: KNN-consistency + prior-filter mask + list compaction (pure; the old
// G->Gn copy is gone -- k_ridge reads G directly / builds Gn only if M>0).
__global__ void k_mask(const int* __restrict__ preds, const void* __restrict__ nearv,
                       const float* __restrict__ coords, const float* __restrict__ normz,
                       int* __restrict__ flags, int* __restrict__ list, int N) {
  int i = blockIdx.x * blockDim.x + threadIdx.x;
  if (i >= N) return;
  int p = preds[i];
  int idx[K_NN];
  if (flags[1]) {
    const longlong2* nn = (const longlong2*)((const long long*)nearv + (long long)i * K_NN);
#pragma unroll
    for (int k = 0; k < K_NN / 2; k++) {
      longlong2 v = nn[k];
      idx[2 * k] = (int)v.x; idx[2 * k + 1] = (int)v.y;
    }
  } else {
    const int4* nn = (const int4*)((const int*)nearv + (size_t)i * K_NN);
#pragma unroll
    for (int k = 0; k < K_NN / 4; k++) {
      int4 v = nn[k];
      idx[4 * k] = v.x; idx[4 * k + 1] = v.y; idx[4 * k + 2] = v.z; idx[4 * k + 3] = v.w;
    }
  }
  int cnt = 0;
#pragma unroll
  for (int k = 0; k < K_NN; k++) cnt += (preds[idx[k]] == p) ? 1 : 0;
  bool cmask = (cnt >= 17);  // cnt/20 > 0.8  <=>  cnt >= 17 (exact in f32)
  bool plane = (p == 2) || (p == 3) || (p == 4);
  bool man   = (p == 5);
  bool other = (p == 0) || (p == 1) || (p == 6);
  float nz = normz[i];
  bool ground = plane && (nz > 0.9f) && (coords[(size_t)i * 3 + 2] < -10.0f);
  bool g = ground || other || man;
  bool m = (man && (nz < 0.1f)) || other || plane;
  if (cmask && g && m) {
    int pos = atomicAdd(&flags[0], 1);
    list[pos] = i;
  }
}

__device__ inline void block_reduce7(const float* val, volatile float* out,
                                     float* red) {
  int lane = threadIdx.x & 63, wave = threadIdx.x >> 6;
#pragma unroll
  for (int c = 0; c < C_CLS; c++) {
    float v = val[c];
#pragma unroll
    for (int o = 32; o > 0; o >>= 1) v += __shfl_down(v, o, 64);
    if (lane == 0) red[wave * C_CLS + c] = v;
  }
  __syncthreads();
  if (threadIdx.x == 0) {
#pragma unroll
    for (int c = 0; c < C_CLS; c++) {
      float s = 0.f;
      for (int wv = 0; wv < 16; wv++) s += red[wv * C_CLS + c];
      out[c] = s;
    }
  }
  __syncthreads();
}

// K3: single block, 1024 threads. Computes b = Qn row in registers (loop over
// masked list). If M>0, builds Gn = G + F^T F in ws (fused, no pre-copy) and
// solves on Gn; if M==0, solves directly on A = G + 100I with ZERO copies.
// Block-CG: A = 100I + PSD, converges in <= M+1 iters exactly; with b=0 the
// done-check exits at iteration 0 -- no row of A is ever read.
__global__ void __launch_bounds__(1024) k_ridge(const float* __restrict__ feat,
                                                const float* __restrict__ w,
                                                const float* __restrict__ Q,
                                                const float* __restrict__ G,
                                                const int* __restrict__ preds,
                                                const int* __restrict__ flags,
                                                const int* __restrict__ list,
                                                float* __restrict__ Gn,
                                                float* __restrict__ wo,
                                                float* __restrict__ wo_flag) {
  const int h = threadIdx.x;
  __shared__ float psh[H_DIM * C_CLS];   // 28 KB (reused: f-staging then CG p)
  __shared__ float red[16 * C_CLS];
  __shared__ float rs[C_CLS], bn2[C_CLS], pap[C_CLS], rsn[C_CLS];

  const int M = flags[0];
  float b[C_CLS];
#pragma unroll
  for (int c = 0; c < C_CLS; c++) b[c] = Q[h * C_CLS + c];
  const float* Amat = G;  // M==0: read input Gram directly (no copy)
  if (M > 0) {
    for (int m = 0; m < M; m++) {
      int i = list[m];
      float s = 0.f;
      for (int d = 0; d < D_DIM; d++)
        s += feat[(size_t)i * D_DIM + d] * w[(size_t)d * H_DIM + h];
      s = fmaxf(s, 0.f);
      b[preds[i]] += s;
      psh[h] = s;
      __syncthreads();
      float sh = psh[h];
      if (m == 0) {
        for (int k = 0; k < H_DIM; k++)
          Gn[(size_t)h * H_DIM + k] = G[(size_t)h * H_DIM + k] + sh * psh[k];
      } else {
        for (int k = 0; k < H_DIM; k++)
          Gn[(size_t)h * H_DIM + k] += sh * psh[k];
      }
      __syncthreads();
    }
    Amat = Gn;
  }

  float x[C_CLS], r[C_CLS], p[C_CLS], t7[C_CLS];
#pragma unroll
  for (int c = 0; c < C_CLS; c++) {
    x[c] = 0.f; r[c] = b[c]; p[c] = b[c];
    t7[c] = b[c] * b[c];
  }
  block_reduce7(t7, rs, red);
  if (h == 0) {
#pragma unroll
    for (int c = 0; c < C_CLS; c++) bn2[c] = rs[c];
  }
  __syncthreads();

  for (int it = 0; it < H_DIM; it++) {
    bool done = true;
#pragma unroll
    for (int c = 0; c < C_CLS; c++)
      done = done && (rs[c] <= bn2[c] * 1e-16f + 1e-30f);
    if (done) break;  // uniform: rs/bn2 live in LDS

#pragma unroll
    for (int c = 0; c < C_CLS; c++) psh[h * C_CLS + c] = p[c];
    __syncthreads();

    float ap[C_CLS];
#pragma unroll
    for (int c = 0; c < C_CLS; c++) ap[c] = 100.0f * p[c];
    const float* grow = Amat + (size_t)h * H_DIM;
    for (int k = 0; k < H_DIM; k++) {
      float g = grow[k];
#pragma unroll
      for (int c = 0; c < C_CLS; c++) ap[c] += g * psh[k * C_CLS + c];
    }
#pragma unroll
    for (int c = 0; c < C_CLS; c++) t7[c] = p[c] * ap[c];
    block_reduce7(t7, pap, red);

    float a[C_CLS], rsold[C_CLS];
#pragma unroll
    for (int c = 0; c < C_CLS; c++) {
      rsold[c] = rs[c];
      bool act = rs[c] > bn2[c] * 1e-16f + 1e-30f;
      a[c] = act ? rsold[c] / fmaxf(pap[c], 1e-37f) : 0.f;
    }
#pragma unroll
    for (int c = 0; c < C_CLS; c++) {
      x[c] += a[c] * p[c];
      r[c] -= a[c] * ap[c];
      t7[c] = r[c] * r[c];
    }
    block_reduce7(t7, rsn, red);
#pragma unroll
    for (int c = 0; c < C_CLS; c++) {
      float bb = rsn[c] / fmaxf(rsold[c], 1e-37f);
      p[c] = r[c] + bb * p[c];
    }
    if (h == 0) {
#pragma unroll
      for (int c = 0; c < C_CLS; c++) rs[c] = rsn[c];
    }
    __syncthreads();
  }

#pragma unroll
  for (int c = 0; c < C_CLS; c++) wo[h * C_CLS + c] = x[c];
  float s = 0.f;
#pragma unroll
  for (int c = 0; c < C_CLS; c++) s += fabsf(x[c]);
  t7[0] = s;
#pragma unroll
  for (int c = 1; c < C_CLS; c++) t7[c] = 0.f;
  block_reduce7(t7, rsn, red);
  if (h == 0) *wo_flag = rsn[0];
}

// K4: out[i][c] = sum_h relu(feat_i . W[:,h]) * wo[h][c]. If wo == 0 (the
// data-driven common case here), this is exactly a grid-stride float4 zero
// fill (N*C = 700000 floats = 175000 float4s).
__global__ void k_out(const float* __restrict__ feat, const float* __restrict__ w,
                      const float* __restrict__ wo, const float* __restrict__ wo_flag,
                      float* __restrict__ out, int N) {
  if (*wo_flag == 0.0f) {
    int total4 = (N * C_CLS) / 4;  // 700000 % 4 == 0
    int stride = gridDim.x * blockDim.x;
    float4 z = make_float4(0.f, 0.f, 0.f, 0.f);
    for (int v = blockIdx.x * blockDim.x + threadIdx.x; v < total4; v += stride)
      ((float4*)out)[v] = z;
    return;
  }
  int i = blockIdx.x * blockDim.x + threadIdx.x;
  if (i >= N) return;
  float f[D_DIM];
  const float4* fp = (const float4*)(feat + (size_t)i * D_DIM);
#pragma unroll
  for (int q = 0; q < D_DIM / 4; q++) {
    float4 v = fp[q];
    f[4 * q] = v.x; f[4 * q + 1] = v.y; f[4 * q + 2] = v.z; f[4 * q + 3] = v.w;
  }
  float acc[C_CLS];
#pragma unroll
  for (int c = 0; c < C_CLS; c++) acc[c] = 0.f;
  for (int hh = 0; hh < H_DIM; hh++) {
    float s = 0.f;
#pragma unroll 8
    for (int d = 0; d < D_DIM; d++) s += f[d] * w[(size_t)d * H_DIM + hh];
    s = fmaxf(s, 0.f);
    const float* wrow = wo + hh * C_CLS;
#pragma unroll
    for (int c = 0; c < C_CLS; c++) acc[c] += s * wrow[c];
  }
#pragma unroll
  for (int c = 0; c < C_CLS; c++) out[(size_t)i * C_CLS + c] = acc[c];
}

extern "C" void kernel_launch(void* const* d_in, const int* in_sizes, int n_in,
                              void* d_out, int out_size, void* d_ws, size_t ws_size,
                              hipStream_t stream) {
  const float* feat   = (const float*)d_in[0];
  const float* proto  = (const float*)d_in[1];
  const float* w      = (const float*)d_in[2];
  const float* Q      = (const float*)d_in[3];
  const float* G      = (const float*)d_in[4];
  const float* coords = (const float*)d_in[5];
  const float* normz  = (const float*)d_in[6];
  const void*  nearv  = d_in[7];
  float* out = (float*)d_out;

  const int N = in_sizes[0] / D_DIM;  // 100000

  char* WS = (char*)d_ws;
  int*   flags   = (int*)(WS + 4096);
  float* wo_flag = (float*)(WS + 4160);
  int*   preds   = (int*)(WS + 8192);
  int*   list    = (int*)(WS + 8192 + 400000);
  float* wo      = (float*)(WS + 836864);
  float* Gn      = (float*)(WS + 865536);
  // total ws need: 5059840 bytes
  if (ws_size < 5059840) return;  // constant per session; visible failure if hit

  int nblk = (N + 255) / 256;  // 391 blocks: 1.5 blocks/CU, all CUs active
  hipLaunchKernelGGL(k_preds, dim3(nblk), dim3(256), 0, stream,
                     feat, proto, (const long long*)nearv, preds, flags, N);
  hipLaunchKernelGGL(k_mask, dim3(nblk), dim3(256), 0, stream,
                     preds, nearv, coords, normz, flags, list, N);
  hipLaunchKernelGGL(k_ridge, dim3(1), dim3(1024), 0, stream,
                     feat, w, Q, G, preds, flags, list, Gn, wo, wo_flag);
  int oblk = ((N * C_CLS) / 4 + 255) / 256;  // 684 blocks for the fill path
  hipLaunchKernelGGL(k_out, dim3(oblk), dim3(256), 0, stream,
                     feat, w, wo, wo_flag, out, N);
}